// Round 4
// baseline (212.112 us; speedup 1.0000x reference)
//
#include <hip/hip_runtime.h>
#include <hip/hip_bf16.h>

// Problem constants (from reference)
#define MA 60000
#define PA 20
#define CA 5
#define MR 80000
#define PR 32
#define CR 3
#define NXg 256
#define NYg 256
#define NB 8
#define NCELL (NB * NYg * NXg)   // 524288

typedef __bf16 bf16x8 __attribute__((ext_vector_type(8)));
typedef float  f32x4  __attribute__((ext_vector_type(4)));
typedef float  f4     __attribute__((ext_vector_type(4)));
typedef float  f2     __attribute__((ext_vector_type(2)));

__device__ __forceinline__ unsigned short f2bf(float f) {
    unsigned int u = __float_as_uint(f);
    u += 0x7fffu + ((u >> 16) & 1u);   // round-to-nearest-even
    return (unsigned short)(u >> 16);
}

// ---------------------------------------------------------------------------
// prep: conv-weight B-fragment pack only (win init moved to hipMemsetAsync).
// Pack order: offset = tap*4096 + kk*1024 + nt*512 + lane*8 + j,
// with n = nt*16+(lane&15), k = kk*32+(lane>>4)*8+j.
__global__ void __launch_bounds__(256) prep_kernel(const float* __restrict__ conv_w,
                                                   unsigned short* __restrict__ bp) {
    int i = blockIdx.x * 256 + threadIdx.x;    // < 144*256 = 36864 exactly
    int j    = i & 7;
    int lane = (i >> 3) & 63;
    int nt   = (i >> 9) & 1;
    int kk   = (i >> 10) & 3;
    int tap  = i >> 12;
    int n = nt * 16 + (lane & 15);
    int k = kk * 32 + (lane >> 4) * 8 + j;
    bp[i] = f2bf(conv_w[(tap * 128 + k) * 32 + n]);
}

// ---------------------------------------------------------------------------
// Pillar VFE v9: 128-thread blocks, 32 pillars/block (12.8 KB LDS -> 12
// blocks/CU), agent/rg interleaved 3:4 across the grid for tail balance.
// Staging: chunk-transpose (compile-time shuffle, b128 LDS writes).
// LDS layout per pillar: [c][pt], PMAXp (mult of 4) points per channel.
// Invalid slots [np, 4*ceil(np/4)) hold copies of point 0 -> max unchanged,
// sums corrected by (np4-np)*v0.
template <int CIN, int CF, int PMAX, int PMAXp>
__device__ __forceinline__ void vfe_body(
    int bid, const float* __restrict__ vox, const int* __restrict__ coors,
    const int* __restrict__ npts, const float* __restrict__ W,
    const float* __restrict__ bias, unsigned short* __restrict__ feat,
    int* __restrict__ win, int M, int which, f4* sq)
{
    constexpr int PC   = PMAX * CIN;       // floats per pillar (source)
    constexpr int SR   = PMAXp * CIN;      // floats per pillar (LDS region)
    constexpr int SR4  = SR / 4;
    constexpr int PP4  = PMAXp / 4;
    constexpr int CPP  = PMAX / 4;         // staged 4-point chunks per pillar
    constexpr int NP   = 32;               // pillars per block

    float* sf = (float*)sq;
    int tid  = threadIdx.x;                // 0..127
    int wv   = tid >> 6;                   // 0..1
    int lane = tid & 63;
    int base = bid * NP;
    int cnt  = M - base; cnt = cnt > NP ? NP : cnt;

    // ---- staging: one thread per 4-point chunk; global f4s are contiguous
    // (src = gv + chunk*CIN); transpose to channel-major entirely with
    // compile-time component indices; CIN aligned ds_write_b128 per chunk.
    {
        const f4* gv = (const f4*)vox + (size_t)base * (PC / 4);
        int totc = cnt * CPP;
        for (int c0 = tid; c0 < totc; c0 += 128) {
            int p = c0 / CPP;              // CPP=8 -> shift; CPP=5 -> magic mul
            int g = c0 - p * CPP;
            const f4* src = gv + c0 * CIN;
            f4 q[CIN];
#pragma unroll
            for (int t = 0; t < CIN; ++t) q[t] = src[t];
            float* dst = sf + p * SR + g * 4;
#pragma unroll
            for (int cch = 0; cch < CIN; ++cch) {
                f4 w;
#pragma unroll
                for (int j = 0; j < 4; ++j) {
                    int e = j * CIN + cch;         // compile-time after unroll
                    w[j] = q[e >> 2][e & 3];
                }
                *(f4*)(dst + cch * PMAXp) = w;     // 16B-aligned for all params
            }
        }
    }

    // per-lane weight column + effective (folded) weights (overlaps staging)
    float wc[CF];
#pragma unroll
    for (int c = 0; c < CF; ++c) wc[c] = W[c * 64 + lane];
    float bd = bias[lane];
    f2 we2[CIN];
    we2[0] = (f2){wc[0] + wc[CIN + 0] + wc[CIN + 3], wc[0] + wc[CIN + 0] + wc[CIN + 3]};
    we2[1] = (f2){wc[1] + wc[CIN + 1] + wc[CIN + 4], wc[1] + wc[CIN + 1] + wc[CIN + 4]};
    we2[2] = (f2){wc[2] + wc[CIN + 2], wc[2] + wc[CIN + 2]};
#pragma unroll
    for (int c = 3; c < CIN; ++c) we2[c] = (f2){wc[c], wc[c]};

    __syncthreads();

    // ---- dup-fill: lane per pillar copies point 0 into [np, np4) ----
    if (tid < cnt) {
        int np = npts[base + tid];
        np = np < 1 ? 1 : (np > PMAX ? PMAX : np);
        int np4 = (np + 3) & ~3;           // <= PMAXp
        float v0[CIN];
#pragma unroll
        for (int c = 0; c < CIN; ++c) v0[c] = sf[tid * SR + c * PMAXp];
        for (int p = np; p < np4; ++p)
#pragma unroll
            for (int c = 0; c < CIN; ++c)
                sf[tid * SR + c * PMAXp + p] = v0[c];
    }
    __syncthreads();

    // ---- meta prefetch (wave-uniform scalar loads) ----
    int np_n = 1, cb_n = 0, cy_n = 0, cx_n = 0;
    if (wv < cnt) {
        np_n = npts[base + wv];
        cb_n = coors[(base + wv) * 3 + 0];
        cy_n = coors[(base + wv) * 3 + 1];
        cx_n = coors[(base + wv) * 3 + 2];
    }

    // ---- compute: 16 pillars per wave, maskless pk math, 4-pt groups ----
    for (int pi = wv; pi < cnt; pi += 2) {
        int np = np_n, cb = cb_n, cy = cy_n, cx = cx_n;
        int pn = pi + 2;
        if (pn < cnt) {
            np_n = npts[base + pn];
            cb_n = coors[(base + pn) * 3 + 0];
            cy_n = coors[(base + pn) * 3 + 1];
            cx_n = coors[(base + pn) * 3 + 2];
        }
        np = np < 1 ? 1 : (np > PMAX ? PMAX : np);
        int nblk = (np + 3) >> 2;
        float kf = (float)(nblk * 4 - np);

        const f4* pf4 = sq + pi * SR4;
        const float* pf = sf + pi * SR;
        float x0 = pf[0], y0 = pf[PMAXp], z0 = pf[2 * PMAXp];

        f2 sx2 = {0.f, 0.f}, sy2 = {0.f, 0.f}, sz2 = {0.f, 0.f};
        f2 b2  = {-1e30f, -1e30f};

        for (int g = 0; g < nblk; ++g) {   // 4 points per group
            f4 v[CIN];
#pragma unroll
            for (int c = 0; c < CIN; ++c) v[c] = pf4[c * PP4 + g];
#pragma unroll
            for (int j = 0; j < 2; ++j) {  // point pair within group
                f2 x2 = (f2){v[0][2*j], v[0][2*j+1]};
                f2 y2 = (f2){v[1][2*j], v[1][2*j+1]};
                f2 z2 = (f2){v[2][2*j], v[2][2*j+1]};
                sx2 += x2; sy2 += y2; sz2 += z2;
                f2 d2 = x2 * we2[0] + y2 * we2[1] + z2 * we2[2];
#pragma unroll
                for (int c = 3; c < CIN; ++c) {
                    f2 e2 = (f2){v[c][2*j], v[c][2*j+1]};
                    d2 += e2 * we2[c];
                }
                b2 = __builtin_elementwise_max(b2, d2);
            }
        }

        // dup-corrected sums; max unaffected by dups of point 0
        float sx = sx2[0] + sx2[1] - kf * x0;
        float sy = sy2[0] + sy2[1] - kf * y0;
        float sz = sz2[0] + sz2[1] - kf * z0;
        float sbest = fmaxf(b2[0], b2[1]);

        float inv = 1.0f / (float)np;
        float mx = sx * inv, my = sy * inv, mz = sz * inv;
        float xo = (float)cx * 0.3125f + (-39.84375f);   // VX, X_OFF exact
        float yo = (float)cy * 0.3125f + (-19.84375f);
        float off = bd - (mx * wc[CIN + 0] + my * wc[CIN + 1] + mz * wc[CIN + 2])
                       - xo * wc[CIN + 3] - yo * wc[CIN + 4];
        float best = fmaxf(0.0f, sbest + off);

        feat[(size_t)(base + pi) * 64 + lane] = f2bf(best);

        if (lane == 0) {
            // numpy last-write-wins == max pillar index wins; int2 map
            atomicMax(&win[((cb * NYg + cy) * NXg + cx) * 2 + which], base + pi);
        }
    }
}

// Unified VFE launch: 4375 blocks of 128 threads, agent:rg interleaved 3:4.
// Agent blocks: 60000/32 = 1875; rg blocks: 80000/32 = 2500; 1875:2500 = 3:4.
// LDS 12800 B -> 12 blocks/CU (24 waves, 75% occupancy cap).
__global__ void __launch_bounds__(128) vfe_all(
    const float* __restrict__ vox_a, const int* __restrict__ coor_a,
    const int* __restrict__ np_a, const float* __restrict__ w_a,
    const float* __restrict__ b_a, unsigned short* __restrict__ feat_a,
    const float* __restrict__ vox_r, const int* __restrict__ coor_r,
    const int* __restrict__ np_r, const float* __restrict__ w_r,
    const float* __restrict__ b_r, unsigned short* __restrict__ feat_r,
    int* __restrict__ win)
{
    __shared__ f4 sq[32 * 25];             // 12800 B (agent: 32*100 floats)
    int bid = blockIdx.x;
    int g = bid / 7, r = bid - g * 7;
    if (r < 3)
        vfe_body<CA, CA + 5, PA, 20>(g * 3 + r, vox_a, coor_a, np_a, w_a, b_a,
                                     feat_a, win, MA, 0, sq);
    else
        vfe_body<CR, CR + 5, PR, 32>(g * 4 + (r - 3), vox_r, coor_r, np_r, w_r, b_r,
                                     feat_r, win, MR, 1, sq);
}

// ---------------------------------------------------------------------------
// Conv v4 (unchanged): 4 channel-phases of 32, block = 4 rows x 64
// cells, 396-cell halo staged via winner map into LDS (80 B cell stride).
__global__ void __launch_bounds__(256) conv_kernel(
    const unsigned short* __restrict__ feat_a,
    const unsigned short* __restrict__ feat_r,
    const int2* __restrict__ win2,            // {agent, rg} per cell
    const unsigned short* __restrict__ bpack,
    const float* __restrict__ conv_b,
    float* __restrict__ out)
{
    __shared__ uint4 sA[396 * 5];             // 31,680 B (5th uint4 = pad)

    int tid  = threadIdx.x;
    int lane = tid & 63;
    int wv   = tid >> 6;
    int bid  = blockIdx.x;
    int xg = bid & 3, yg = (bid >> 2) & 63, b = bid >> 8;
    int x0 = xg * 64, y0 = yg * 4;
    int mrow = lane & 15, quad = lane >> 4;

    // winner indices for this thread's (up to) 2 halo cells — loaded ONCE
    int wA[2] = {-1, -1}, wR[2] = {-1, -1};
#pragma unroll
    for (int r = 0; r < 2; ++r) {
        int cell = tid + r * 256;
        if (cell < 396) {
            int iy = cell / 66, ix = cell - iy * 66;
            int yy = y0 - 1 + iy, xx = x0 - 1 + ix;
            if ((unsigned)yy < 256u && (unsigned)xx < 256u) {
                int2 w2 = win2[(((b << 8) + yy) << 8) + xx];
                wA[r] = w2.x; wR[r] = w2.y;
            }
        }
    }

    f32x4 acc0[4], acc1[4];
#pragma unroll
    for (int mt = 0; mt < 4; ++mt) {
        acc0[mt] = (f32x4){0.f, 0.f, 0.f, 0.f};
        acc1[mt] = (f32x4){0.f, 0.f, 0.f, 0.f};
    }

#pragma unroll
    for (int ph = 0; ph < 4; ++ph) {
        const unsigned short* feat = (ph < 2) ? feat_a : feat_r;
        const int half = (ph & 1) * 32;       // channel offset within feat row

        // ---- stage this phase's 32 channels for all 396 halo cells ----
#pragma unroll
        for (int r = 0; r < 2; ++r) {
            int cell = tid + r * 256;
            if (cell < 396) {
                int w = (ph < 2) ? wA[r] : wR[r];
                uint4* dst = &sA[cell * 5];
                if (w >= 0) {
                    const uint4* src = (const uint4*)(feat + ((long)w << 6) + half);
                    dst[0] = src[0]; dst[1] = src[1];
                    dst[2] = src[2]; dst[3] = src[3];
                } else {
                    uint4 zz = {0, 0, 0, 0};
                    dst[0] = zz; dst[1] = zz; dst[2] = zz; dst[3] = zz;
                }
            }
        }
        __syncthreads();

        // ---- compute: kk = ph, 9 taps x 4 Mtiles x 2 Ntiles ----
#pragma unroll
        for (int tap = 0; tap < 9; ++tap) {
            const int dyo = tap / 3, dxo = tap % 3;
            const unsigned short* bp = bpack + tap * 4096 + ph * 1024 + lane * 8;
            bf16x8 bn0 = *(const bf16x8*)(bp);
            bf16x8 bn1 = *(const bf16x8*)(bp + 512);
            int iy = wv + dyo;
#pragma unroll
            for (int mt = 0; mt < 4; ++mt) {
                int ix = mt * 16 + mrow + dxo;
                bf16x8 a = *(const bf16x8*)(&sA[(iy * 66 + ix) * 5 + quad]);
                acc0[mt] = __builtin_amdgcn_mfma_f32_16x16x32_bf16(a, bn0, acc0[mt], 0, 0, 0);
                acc1[mt] = __builtin_amdgcn_mfma_f32_16x16x32_bf16(a, bn1, acc1[mt], 0, 0, 0);
            }
        }
        __syncthreads();
    }

    // ---- Epilogue: D layout col=lane&15, row=quad*4+reg ----
    int col = lane & 15;
    float bias0 = conv_b[col];
    float bias1 = conv_b[col + 16];
    int cellbase = ((((b << 8) + y0 + wv)) << 8) + x0;
#pragma unroll
    for (int mt = 0; mt < 4; ++mt) {
#pragma unroll
        for (int r = 0; r < 4; ++r) {
            int cell = cellbase + mt * 16 + quad * 4 + r;
            float* o = out + (long)cell * 32;
            o[col]      = acc0[mt][r] + bias0;
            o[col + 16] = acc1[mt][r] + bias1;
        }
    }
}

// ---------------------------------------------------------------------------
extern "C" void kernel_launch(void* const* d_in, const int* in_sizes, int n_in,
                              void* d_out, int out_size, void* d_ws, size_t ws_size,
                              hipStream_t stream)
{
    const float* vox_a  = (const float*)d_in[0];
    const int*   coor_a = (const int*)d_in[1];
    const int*   np_a   = (const int*)d_in[2];
    const float* vox_r  = (const float*)d_in[3];
    const int*   coor_r = (const int*)d_in[4];
    const int*   np_r   = (const int*)d_in[5];
    const float* w_a    = (const float*)d_in[6];
    const float* b_a    = (const float*)d_in[7];
    const float* w_r    = (const float*)d_in[8];
    const float* b_r    = (const float*)d_in[9];
    const float* conv_w = (const float*)d_in[10];
    const float* conv_b = (const float*)d_in[11];
    float* out = (float*)d_out;

    // Workspace layout (16B-aligned offsets), total ~22.2 MB
    char* ws = (char*)d_ws;
    unsigned short* feat_a = (unsigned short*)(ws);                          // 7,680,000 B
    unsigned short* feat_r = (unsigned short*)(ws + 7680000);                // 10,240,000 B
    int* win               = (int*)(ws + 17920000);                          // 4,194,304 B (int2/cell)
    unsigned short* bpack  = (unsigned short*)(ws + 17920000 + 4194304);     // 73,728 B

    // 1a) winner map = -1 via DMA memset (0xFF bytes == -1 int), capture-safe
    hipMemsetAsync(win, 0xFF, 2 * (size_t)NCELL * sizeof(int), stream);
    // 1b) prep: weight pack only (144 blocks)
    hipLaunchKernelGGL(prep_kernel, dim3(144), dim3(256), 0, stream,
                       conv_w, bpack);
    // 2) unified VFE: 4375 x 128-thread blocks, agent:rg interleaved 3:4
    hipLaunchKernelGGL(vfe_all, dim3(MA / 32 + MR / 32), dim3(128), 0, stream,
                       vox_a, coor_a, np_a, w_a, b_a, feat_a,
                       vox_r, coor_r, np_r, w_r, b_r, feat_r, win);
    // 3) conv v4: block = 4 rows x 64 cells, 4 channel-phases
    hipLaunchKernelGGL(conv_kernel, dim3(2048), dim3(256), 0, stream,
                       feat_a, feat_r, (const int2*)win, bpack, conv_b, out);
}

// Round 5
// 198.689 us; speedup vs baseline: 1.0676x; 1.0676x over previous
//
#include <hip/hip_runtime.h>
#include <hip/hip_bf16.h>

// Problem constants (from reference)
#define MA 60000
#define PA 20
#define CA 5
#define MR 80000
#define PR 32
#define CR 3
#define NXg 256
#define NYg 256
#define NB 8
#define NCELL (NB * NYg * NXg)   // 524288

typedef __bf16 bf16x8 __attribute__((ext_vector_type(8)));
typedef float  f32x4  __attribute__((ext_vector_type(4)));
typedef float  f4     __attribute__((ext_vector_type(4)));
typedef float  f2     __attribute__((ext_vector_type(2)));

__device__ __forceinline__ unsigned short f2bf(float f) {
    unsigned int u = __float_as_uint(f);
    u += 0x7fffu + ((u >> 16) & 1u);   // round-to-nearest-even
    return (unsigned short)(u >> 16);
}

// ---------------------------------------------------------------------------
// prep: conv-weight B-fragment pack only (win init via hipMemsetAsync).
// Pack order: offset = tap*4096 + kk*1024 + nt*512 + lane*8 + j,
// with n = nt*16+(lane&15), k = kk*32+(lane>>4)*8+j.
__global__ void __launch_bounds__(256) prep_kernel(const float* __restrict__ conv_w,
                                                   unsigned short* __restrict__ bp) {
    int i = blockIdx.x * 256 + threadIdx.x;    // < 144*256 = 36864 exactly
    int j    = i & 7;
    int lane = (i >> 3) & 63;
    int nt   = (i >> 9) & 1;
    int kk   = (i >> 10) & 3;
    int tap  = i >> 12;
    int n = nt * 16 + (lane & 15);
    int k = kk * 32 + (lane >> 4) * 8 + j;
    bp[i] = f2bf(conv_w[(tap * 128 + k) * 32 + n]);
}

// ---------------------------------------------------------------------------
// Pillar VFE v10: BARRIER-FREE wave-private design.
// Each wave owns 16 pillars + a private LDS slot; stage -> dup-fill+means ->
// compute all ordered by the wave's own in-order LDS pipe (no __syncthreads).
// Staging skips fully-invalid chunks (4g >= np). Means computed ONCE per
// pillar by the dup-fill lane (dup-corrected f4 sums / np) and broadcast via
// LDS, so the inner loop is dot+max only (no redundant per-lane sum chains).
template <int CIN, int CF, int PMAX, int PMAXp, int WSLOT>
__device__ __forceinline__ void vfe_wave(
    int wpid, const float* __restrict__ vox, const int* __restrict__ coors,
    const int* __restrict__ npts, const float* __restrict__ W,
    const float* __restrict__ bias, unsigned short* __restrict__ feat,
    int* __restrict__ win, int M, int which, float* __restrict__ ws)
{
    constexpr int SR    = PMAXp * CIN;        // floats per pillar (LDS region)
    constexpr int SR4   = SR / 4;
    constexpr int PP4   = PMAXp / 4;
    constexpr int CPP   = PMAX / 4;           // 4-point chunks per pillar
    constexpr int MEANOFF = 16 * SR;          // floats; 16 x f4 means
    constexpr int CITER = (16 * CPP + 63) / 64;

    int lane = threadIdx.x & 63;
    int base = wpid * 16;
    if (base >= M) return;
    int cnt = M - base; cnt = cnt > 16 ? 16 : cnt;

    f4* sq    = (f4*)ws;
    f4* mean4 = (f4*)(ws + MEANOFF);

    // ---- per-lane weight column + folded weights (no LDS dependency) ----
    float wc[CF];
#pragma unroll
    for (int c = 0; c < CF; ++c) wc[c] = W[c * 64 + lane];
    float bd = bias[lane];
    f2 we2[CIN];
    we2[0] = (f2){wc[0] + wc[CIN + 0] + wc[CIN + 3], wc[0] + wc[CIN + 0] + wc[CIN + 3]};
    we2[1] = (f2){wc[1] + wc[CIN + 1] + wc[CIN + 4], wc[1] + wc[CIN + 1] + wc[CIN + 4]};
    we2[2] = (f2){wc[2] + wc[CIN + 2], wc[2] + wc[CIN + 2]};
#pragma unroll
    for (int c = 3; c < CIN; ++c) we2[c] = (f2){wc[c], wc[c]};

    // ---- staging: one lane per 4-point chunk; skip fully-invalid chunks ----
    {
        const f4* gv = (const f4*)vox + (size_t)base * (CPP * CIN);
        int totc = cnt * CPP;
#pragma unroll
        for (int it = 0; it < CITER; ++it) {
            int c0 = it * 64 + lane;
            if (c0 < totc) {
                int p = c0 / CPP;              // compile-time-const divisor
                int g = c0 - p * CPP;
                int npc = npts[base + p];
                npc = npc < 1 ? 1 : (npc > PMAX ? PMAX : npc);
                if (g * 4 < npc) {             // chunk has >=1 valid point
                    const f4* src = gv + c0 * CIN;
                    f4 q[CIN];
#pragma unroll
                    for (int t = 0; t < CIN; ++t) q[t] = src[t];
                    float* dst = (float*)sq + p * SR + g * 4;
#pragma unroll
                    for (int cch = 0; cch < CIN; ++cch) {
                        f4 w;
#pragma unroll
                        for (int j = 0; j < 4; ++j) {
                            int e = j * CIN + cch;     // compile-time
                            w[j] = q[e >> 2][e & 3];
                        }
                        *(f4*)(dst + cch * PMAXp) = w; // 16B-aligned always
                    }
                }
            }
        }
    }

    // ---- dup-fill + per-pillar mean (one lane per pillar; same-wave order
    //      guarantees staging writes are visible) ----
    if (lane < cnt) {
        int np = npts[base + lane];
        np = np < 1 ? 1 : (np > PMAX ? PMAX : np);
        int np4 = (np + 3) & ~3;
        int nblk = np4 >> 2;
        float* pb = (float*)sq + lane * SR;
        float v0[CIN];
#pragma unroll
        for (int c = 0; c < CIN; ++c) v0[c] = pb[c * PMAXp];
        for (int p = np; p < np4; ++p)
#pragma unroll
            for (int c = 0; c < CIN; ++c) pb[c * PMAXp + p] = v0[c];
        // sums over np4 points (dups of point0 included), then correct
        const f4* pb4 = (const f4*)pb;
        f4 ax = {0.f,0.f,0.f,0.f}, ay = {0.f,0.f,0.f,0.f}, az = {0.f,0.f,0.f,0.f};
        for (int g = 0; g < nblk; ++g) {
            ax += pb4[0 * PP4 + g];
            ay += pb4[1 * PP4 + g];
            az += pb4[2 * PP4 + g];
        }
        float kf = (float)(np4 - np);
        float sx = (ax[0] + ax[1]) + (ax[2] + ax[3]) - kf * v0[0];
        float sy = (ay[0] + ay[1]) + (ay[2] + ay[3]) - kf * v0[1];
        float sz = (az[0] + az[1]) + (az[2] + az[3]) - kf * v0[2];
        float inv = 1.0f / (float)np;
        mean4[lane] = (f4){sx * inv, sy * inv, sz * inv, 0.0f};
    }

    // ---- compute: 16 serial pillars, dot+max only ----
    int np_n = npts[base];
    int cb_n = coors[base * 3 + 0];
    int cy_n = coors[base * 3 + 1];
    int cx_n = coors[base * 3 + 2];

    for (int pi = 0; pi < cnt; ++pi) {
        int np = np_n, cb = cb_n, cy = cy_n, cx = cx_n;
        int pn = pi + 1;
        if (pn < cnt) {
            np_n = npts[base + pn];
            cb_n = coors[(base + pn) * 3 + 0];
            cy_n = coors[(base + pn) * 3 + 1];
            cx_n = coors[(base + pn) * 3 + 2];
        }
        np = np < 1 ? 1 : (np > PMAX ? PMAX : np);
        int nblk = (np + 3) >> 2;

        f4 m4 = mean4[pi];                 // wave-uniform broadcast read
        const f4* pf4 = sq + pi * SR4;
        f2 b2 = {-1e30f, -1e30f};

        for (int g = 0; g < nblk; ++g) {   // 4 points per group
            f4 v[CIN];
#pragma unroll
            for (int c = 0; c < CIN; ++c) v[c] = pf4[c * PP4 + g];
#pragma unroll
            for (int j = 0; j < 2; ++j) {  // point pair within group
                f2 d2 = (f2){v[0][2*j], v[0][2*j+1]} * we2[0]
                      + (f2){v[1][2*j], v[1][2*j+1]} * we2[1]
                      + (f2){v[2][2*j], v[2][2*j+1]} * we2[2];
#pragma unroll
                for (int c = 3; c < CIN; ++c)
                    d2 += (f2){v[c][2*j], v[c][2*j+1]} * we2[c];
                b2 = __builtin_elementwise_max(b2, d2);
            }
        }

        float sbest = fmaxf(b2[0], b2[1]);
        float xo = (float)cx * 0.3125f + (-39.84375f);   // VX, X_OFF exact
        float yo = (float)cy * 0.3125f + (-19.84375f);
        float off = bd - (m4[0] * wc[CIN + 0] + m4[1] * wc[CIN + 1] + m4[2] * wc[CIN + 2])
                       - xo * wc[CIN + 3] - yo * wc[CIN + 4];
        float best = fmaxf(0.0f, sbest + off);

        feat[(size_t)(base + pi) * 64 + lane] = f2bf(best);

        if (lane == 0) {
            // numpy last-write-wins == max pillar index wins; int2 map
            atomicMax(&win[((cb * NYg + cy) * NXg + cx) * 2 + which], base + pi);
        }
    }
}

// Unified VFE launch: 8750 waves (3750 agent + 5000 rg), 4 waves/block,
// interleaved 3:4 (3750:5000 = 3:4 exactly). No __syncthreads anywhere.
// LDS: 4 x 1664 floats = 26624 B -> 6 blocks/CU (24 waves, 75% cap).
__global__ void __launch_bounds__(256, 6) vfe_all(
    const float* __restrict__ vox_a, const int* __restrict__ coor_a,
    const int* __restrict__ np_a, const float* __restrict__ w_a,
    const float* __restrict__ b_a, unsigned short* __restrict__ feat_a,
    const float* __restrict__ vox_r, const int* __restrict__ coor_r,
    const int* __restrict__ np_r, const float* __restrict__ w_r,
    const float* __restrict__ b_r, unsigned short* __restrict__ feat_r,
    int* __restrict__ win)
{
    constexpr int WSLOT = 1664;            // agent: 16*100 + 64 mean floats
    __shared__ float smem[4 * WSLOT];      // 26624 B
    int wv = threadIdx.x >> 6;
    int w  = blockIdx.x * 4 + wv;
    int g7 = w / 7, r7 = w - g7 * 7;
    float* ws = smem + wv * WSLOT;
    if (r7 < 3)
        vfe_wave<CA, CA + 5, PA, 20, WSLOT>(g7 * 3 + r7, vox_a, coor_a, np_a,
                                            w_a, b_a, feat_a, win, MA, 0, ws);
    else
        vfe_wave<CR, CR + 5, PR, 32, WSLOT>(g7 * 4 + (r7 - 3), vox_r, coor_r, np_r,
                                            w_r, b_r, feat_r, win, MR, 1, ws);
}

// ---------------------------------------------------------------------------
// Conv v4 (unchanged): 4 channel-phases of 32, block = 4 rows x 64
// cells, 396-cell halo staged via winner map into LDS (80 B cell stride).
__global__ void __launch_bounds__(256) conv_kernel(
    const unsigned short* __restrict__ feat_a,
    const unsigned short* __restrict__ feat_r,
    const int2* __restrict__ win2,            // {agent, rg} per cell
    const unsigned short* __restrict__ bpack,
    const float* __restrict__ conv_b,
    float* __restrict__ out)
{
    __shared__ uint4 sA[396 * 5];             // 31,680 B (5th uint4 = pad)

    int tid  = threadIdx.x;
    int lane = tid & 63;
    int wv   = tid >> 6;
    int bid  = blockIdx.x;
    int xg = bid & 3, yg = (bid >> 2) & 63, b = bid >> 8;
    int x0 = xg * 64, y0 = yg * 4;
    int mrow = lane & 15, quad = lane >> 4;

    // winner indices for this thread's (up to) 2 halo cells — loaded ONCE
    int wA[2] = {-1, -1}, wR[2] = {-1, -1};
#pragma unroll
    for (int r = 0; r < 2; ++r) {
        int cell = tid + r * 256;
        if (cell < 396) {
            int iy = cell / 66, ix = cell - iy * 66;
            int yy = y0 - 1 + iy, xx = x0 - 1 + ix;
            if ((unsigned)yy < 256u && (unsigned)xx < 256u) {
                int2 w2 = win2[(((b << 8) + yy) << 8) + xx];
                wA[r] = w2.x; wR[r] = w2.y;
            }
        }
    }

    f32x4 acc0[4], acc1[4];
#pragma unroll
    for (int mt = 0; mt < 4; ++mt) {
        acc0[mt] = (f32x4){0.f, 0.f, 0.f, 0.f};
        acc1[mt] = (f32x4){0.f, 0.f, 0.f, 0.f};
    }

#pragma unroll
    for (int ph = 0; ph < 4; ++ph) {
        const unsigned short* feat = (ph < 2) ? feat_a : feat_r;
        const int half = (ph & 1) * 32;       // channel offset within feat row

        // ---- stage this phase's 32 channels for all 396 halo cells ----
#pragma unroll
        for (int r = 0; r < 2; ++r) {
            int cell = tid + r * 256;
            if (cell < 396) {
                int w = (ph < 2) ? wA[r] : wR[r];
                uint4* dst = &sA[cell * 5];
                if (w >= 0) {
                    const uint4* src = (const uint4*)(feat + ((long)w << 6) + half);
                    dst[0] = src[0]; dst[1] = src[1];
                    dst[2] = src[2]; dst[3] = src[3];
                } else {
                    uint4 zz = {0, 0, 0, 0};
                    dst[0] = zz; dst[1] = zz; dst[2] = zz; dst[3] = zz;
                }
            }
        }
        __syncthreads();

        // ---- compute: kk = ph, 9 taps x 4 Mtiles x 2 Ntiles ----
#pragma unroll
        for (int tap = 0; tap < 9; ++tap) {
            const int dyo = tap / 3, dxo = tap % 3;
            const unsigned short* bp = bpack + tap * 4096 + ph * 1024 + lane * 8;
            bf16x8 bn0 = *(const bf16x8*)(bp);
            bf16x8 bn1 = *(const bf16x8*)(bp + 512);
            int iy = wv + dyo;
#pragma unroll
            for (int mt = 0; mt < 4; ++mt) {
                int ix = mt * 16 + mrow + dxo;
                bf16x8 a = *(const bf16x8*)(&sA[(iy * 66 + ix) * 5 + quad]);
                acc0[mt] = __builtin_amdgcn_mfma_f32_16x16x32_bf16(a, bn0, acc0[mt], 0, 0, 0);
                acc1[mt] = __builtin_amdgcn_mfma_f32_16x16x32_bf16(a, bn1, acc1[mt], 0, 0, 0);
            }
        }
        __syncthreads();
    }

    // ---- Epilogue: D layout col=lane&15, row=quad*4+reg ----
    int col = lane & 15;
    float bias0 = conv_b[col];
    float bias1 = conv_b[col + 16];
    int cellbase = ((((b << 8) + y0 + wv)) << 8) + x0;
#pragma unroll
    for (int mt = 0; mt < 4; ++mt) {
#pragma unroll
        for (int r = 0; r < 4; ++r) {
            int cell = cellbase + mt * 16 + quad * 4 + r;
            float* o = out + (long)cell * 32;
            o[col]      = acc0[mt][r] + bias0;
            o[col + 16] = acc1[mt][r] + bias1;
        }
    }
}

// ---------------------------------------------------------------------------
extern "C" void kernel_launch(void* const* d_in, const int* in_sizes, int n_in,
                              void* d_out, int out_size, void* d_ws, size_t ws_size,
                              hipStream_t stream)
{
    const float* vox_a  = (const float*)d_in[0];
    const int*   coor_a = (const int*)d_in[1];
    const int*   np_a   = (const int*)d_in[2];
    const float* vox_r  = (const float*)d_in[3];
    const int*   coor_r = (const int*)d_in[4];
    const int*   np_r   = (const int*)d_in[5];
    const float* w_a    = (const float*)d_in[6];
    const float* b_a    = (const float*)d_in[7];
    const float* w_r    = (const float*)d_in[8];
    const float* b_r    = (const float*)d_in[9];
    const float* conv_w = (const float*)d_in[10];
    const float* conv_b = (const float*)d_in[11];
    float* out = (float*)d_out;

    // Workspace layout (16B-aligned offsets), total ~22.2 MB
    char* ws = (char*)d_ws;
    unsigned short* feat_a = (unsigned short*)(ws);                          // 7,680,000 B
    unsigned short* feat_r = (unsigned short*)(ws + 7680000);                // 10,240,000 B
    int* win               = (int*)(ws + 17920000);                          // 4,194,304 B (int2/cell)
    unsigned short* bpack  = (unsigned short*)(ws + 17920000 + 4194304);     // 73,728 B

    // 1a) winner map = -1 via DMA memset (0xFF bytes == -1 int), capture-safe
    hipMemsetAsync(win, 0xFF, 2 * (size_t)NCELL * sizeof(int), stream);
    // 1b) prep: weight pack only (144 blocks)
    hipLaunchKernelGGL(prep_kernel, dim3(144), dim3(256), 0, stream,
                       conv_w, bpack);
    // 2) unified VFE: 8750 waves = 2188 blocks x 4 waves, agent:rg 3:4
    hipLaunchKernelGGL(vfe_all, dim3((3750 + 5000 + 3) / 4), dim3(256), 0, stream,
                       vox_a, coor_a, np_a, w_a, b_a, feat_a,
                       vox_r, coor_r, np_r, w_r, b_r, feat_r, win);
    // 3) conv v4: block = 4 rows x 64 cells, 4 channel-phases
    hipLaunchKernelGGL(conv_kernel, dim3(2048), dim3(256), 0, stream,
                       feat_a, feat_r, (const int2*)win, bpack, conv_b, out);
}